// Round 1
// baseline (926.616 us; speedup 1.0000x reference)
//
#include <hip/hip_runtime.h>

#define N_NODES 50000
#define N_EDGES 300000
#define DFEAT 256
#define KCAT 512
#define MT 32   // nodes per block in fused kernel

// ---------- kernel 1: histogram of dst ----------
__global__ void k_hist(const int* __restrict__ ei, int* __restrict__ cnt, int E) {
    int e = blockIdx.x * blockDim.x + threadIdx.x;
    if (e < E) atomicAdd(&cnt[ei[2 * e + 1]], 1);
}

// ---------- kernel 2: exclusive scan over cnt (single block, 1024 threads) ----------
__global__ void k_scan(const int* __restrict__ cnt, int* __restrict__ off,
                       int* __restrict__ cursor, int n, int E) {
    __shared__ int lds[1024];
    int t = threadIdx.x;
    int C = (n + 1023) >> 10;            // elems per thread
    int b = t * C;
    int e = b + C; if (e > n) e = n;
    int s = 0;
    for (int i = b; i < e; i++) s += cnt[i];
    lds[t] = s;
    __syncthreads();
    // Hillis-Steele inclusive scan
    for (int d = 1; d < 1024; d <<= 1) {
        int v = (t >= d) ? lds[t - d] : 0;
        __syncthreads();
        lds[t] += v;
        __syncthreads();
    }
    int run = (t == 0) ? 0 : lds[t - 1];
    for (int i = b; i < e; i++) {
        off[i] = run; cursor[i] = run; run += cnt[i];
    }
    if (t == 1023) off[n] = E;
}

// ---------- kernel 3: scatter edge srcs into CSR order ----------
__global__ void k_scatter(const int* __restrict__ ei, int* __restrict__ cursor,
                          int* __restrict__ srcs, int E) {
    int e = blockIdx.x * blockDim.x + threadIdx.x;
    if (e < E) {
        int s = ei[2 * e];
        int d = ei[2 * e + 1];
        int pos = atomicAdd(&cursor[d], 1);
        srcs[pos] = s;
    }
}

// ---------- kernel 4: transpose weights to k-major concat [Wl; Wr] (512 x 256) ----------
__global__ void k_wt(const float* __restrict__ Wl, const float* __restrict__ Wr,
                     float* __restrict__ Wt) {
    int id = blockIdx.x * blockDim.x + threadIdx.x;   // 512*256 elems
    int k = id >> 8;
    int j = id & 255;
    float v = (k < 256) ? Wl[j * 256 + k] : Wr[j * 256 + (k - 256)];
    Wt[id] = v;
}

// ---------- kernel 5: fused aggregation + GEMM ----------
// out[i,:] = (mean_{e in edges(i)} x[src_e]) @ Wl^T + b + x[i] @ Wr^T
//          = Acat[i] (512) dot Wtcat[:, j], Acat = [agg | x]
__global__ __launch_bounds__(256, 2)
void k_fused(const float* __restrict__ x_obj, const float* __restrict__ x_rel,
             const float* __restrict__ Wt_obj, const float* __restrict__ Wt_rel,
             const float* __restrict__ b_obj, const float* __restrict__ b_rel,
             const int* __restrict__ off, const int* __restrict__ srcs,
             float* __restrict__ out, int n) {
    __shared__ float A[MT][KCAT];          // 32 x 512 floats = 64 KB exactly

    const int tz = blockIdx.y;
    const float* __restrict__ x   = tz ? x_rel  : x_obj;
    const float* __restrict__ Wt  = tz ? Wt_rel : Wt_obj;
    const float* __restrict__ bia = tz ? b_rel  : b_obj;
    float* __restrict__ outp = out + (size_t)tz * (size_t)N_NODES * DFEAT;

    const int t = threadIdx.x;
    const int wave = t >> 6, lane = t & 63;
    const int node0 = blockIdx.x * MT;

    // ---- phase 1: per-node mean aggregation + x staging into LDS ----
    const float4* __restrict__ x4 = (const float4*)x;
    for (int il = wave; il < MT; il += 4) {
        int node = node0 + il;
        float4 accv = make_float4(0.f, 0.f, 0.f, 0.f);
        float4 xv   = make_float4(0.f, 0.f, 0.f, 0.f);
        if (node < n) {
            xv = x4[(size_t)node * 64 + lane];
            int eb = off[node], ee = off[node + 1];
            for (int e = eb; e < ee; e++) {
                int s = srcs[e];
                float4 v = x4[(size_t)s * 64 + lane];
                accv.x += v.x; accv.y += v.y; accv.z += v.z; accv.w += v.w;
            }
            float c = (float)(ee - eb);
            float inv = 1.0f / fmaxf(c, 1.0f);
            accv.x *= inv; accv.y *= inv; accv.z *= inv; accv.w *= inv;
        }
        *(float4*)&A[il][4 * lane]       = accv;   // agg in cols [0,256)
        *(float4*)&A[il][256 + 4 * lane] = xv;     // x   in cols [256,512)
    }
    __syncthreads();

    // ---- phase 2: 32x256 GEMM, 4x8 register tile per thread ----
    const int jg = t & 31;     // col group
    const int rg = t >> 5;     // row group
    const int j0 = jg * 8;
    const int r0 = rg * 4;

    float acc[4][8];
    {
        float4 bv0 = *(const float4*)&bia[j0];
        float4 bv1 = *(const float4*)&bia[j0 + 4];
        float bv[8] = {bv0.x, bv0.y, bv0.z, bv0.w, bv1.x, bv1.y, bv1.z, bv1.w};
        #pragma unroll
        for (int r = 0; r < 4; r++)
            #pragma unroll
            for (int c = 0; c < 8; c++) acc[r][c] = bv[c];
    }

    #pragma unroll 4
    for (int k = 0; k < KCAT; k++) {
        float a0 = A[r0 + 0][k];
        float a1 = A[r0 + 1][k];
        float a2 = A[r0 + 2][k];
        float a3 = A[r0 + 3][k];
        float4 w0 = *(const float4*)&Wt[(k << 8) + j0];
        float4 w1 = *(const float4*)&Wt[(k << 8) + j0 + 4];
        float wv[8] = {w0.x, w0.y, w0.z, w0.w, w1.x, w1.y, w1.z, w1.w};
        #pragma unroll
        for (int c = 0; c < 8; c++) {
            acc[0][c] += a0 * wv[c];
            acc[1][c] += a1 * wv[c];
            acc[2][c] += a2 * wv[c];
            acc[3][c] += a3 * wv[c];
        }
    }

    // ---- writeback ----
    #pragma unroll
    for (int r = 0; r < 4; r++) {
        int node = node0 + r0 + r;
        if (node < n) {
            float4 o0 = make_float4(acc[r][0], acc[r][1], acc[r][2], acc[r][3]);
            float4 o1 = make_float4(acc[r][4], acc[r][5], acc[r][6], acc[r][7]);
            float* op = outp + ((size_t)node << 8) + j0;
            *(float4*)op       = o0;
            *(float4*)(op + 4) = o1;
        }
    }
}

extern "C" void kernel_launch(void* const* d_in, const int* in_sizes, int n_in,
                              void* d_out, int out_size, void* d_ws, size_t ws_size,
                              hipStream_t stream) {
    const float* obj  = (const float*)d_in[0];
    const float* rel  = (const float*)d_in[1];
    const int*   ei   = (const int*)d_in[2];
    const float* Wl_o = (const float*)d_in[3];
    const float* bl_o = (const float*)d_in[4];
    const float* Wr_o = (const float*)d_in[5];
    const float* Wl_r = (const float*)d_in[6];
    const float* bl_r = (const float*)d_in[7];
    const float* Wr_r = (const float*)d_in[8];
    float* out = (float*)d_out;

    char* w = (char*)d_ws;
    size_t o = 0;
    auto alloc = [&](size_t b) { size_t r = o; o += (b + 255) & ~(size_t)255; return r; };
    int*   cnt    = (int*)(w + alloc((size_t)N_NODES * 4));
    int*   off    = (int*)(w + alloc((size_t)(N_NODES + 1) * 4));
    int*   cursor = (int*)(w + alloc((size_t)N_NODES * 4));
    int*   srcs   = (int*)(w + alloc((size_t)N_EDGES * 4));
    float* Wt_o   = (float*)(w + alloc((size_t)KCAT * DFEAT * 4));
    float* Wt_r   = (float*)(w + alloc((size_t)KCAT * DFEAT * 4));

    hipMemsetAsync(cnt, 0, (size_t)N_NODES * 4, stream);
    k_hist<<<(N_EDGES + 255) / 256, 256, 0, stream>>>(ei, cnt, N_EDGES);
    k_scan<<<1, 1024, 0, stream>>>(cnt, off, cursor, N_NODES, N_EDGES);
    k_scatter<<<(N_EDGES + 255) / 256, 256, 0, stream>>>(ei, cursor, srcs, N_EDGES);
    k_wt<<<(KCAT * DFEAT) / 256, 256, 0, stream>>>(Wl_o, Wr_o, Wt_o);
    k_wt<<<(KCAT * DFEAT) / 256, 256, 0, stream>>>(Wl_r, Wr_r, Wt_r);

    dim3 g((N_NODES + MT - 1) / MT, 2);
    k_fused<<<g, 256, 0, stream>>>(obj, rel, Wt_o, Wt_r, bl_o, bl_r, off, srcs, out, N_NODES);
}

// Round 3
// 461.493 us; speedup vs baseline: 2.0079x; 2.0079x over previous
//
#include <hip/hip_runtime.h>

#define N_NODES 50000
#define N_EDGES 300000
#define DFEAT 256
#define KCAT 512
#define MT 32          // nodes per block in fused kernel
#define APAD 8         // bf16 row padding: row stride 520*2=1040 B (16B-aligned, bank offset/row)
#define AROW (KCAT + APAD)

typedef __attribute__((ext_vector_type(8))) short bf16x8;
typedef __attribute__((ext_vector_type(4))) float f32x4;

__device__ __forceinline__ unsigned short f2bf(float f) {
    union { float f; unsigned int u; } c; c.f = f;
    unsigned int r = c.u + 0x7FFF + ((c.u >> 16) & 1);   // round-to-nearest-even
    return (unsigned short)(r >> 16);
}

// ---------- kernel 0: zero the CSR workspace region (cnt/off/cursor/srcs) ----------
__global__ void k_zero(int4* __restrict__ p, int n4) {
    int i = blockIdx.x * blockDim.x + threadIdx.x;
    int stride = gridDim.x * blockDim.x;
    for (; i < n4; i += stride) p[i] = make_int4(0, 0, 0, 0);
}

// ---------- kernel 1: histogram of dst (guarded) ----------
__global__ void k_hist(const int* __restrict__ ei, int* __restrict__ cnt, int E) {
    int e = blockIdx.x * blockDim.x + threadIdx.x;
    if (e < E) {
        unsigned d = (unsigned)ei[2 * e + 1];
        if (d < (unsigned)N_NODES) atomicAdd(&cnt[d], 1);
    }
}

// ---------- kernel 2: exclusive scan over cnt (single block, 1024 threads) ----------
__global__ void k_scan(const int* __restrict__ cnt, int* __restrict__ off,
                       int* __restrict__ cursor, int n, int E) {
    __shared__ int lds[1024];
    int t = threadIdx.x;
    int C = (n + 1023) >> 10;
    int b = t * C;
    int e = b + C; if (e > n) e = n;
    if (b > n) b = n;
    int s = 0;
    for (int i = b; i < e; i++) s += cnt[i];
    lds[t] = s;
    __syncthreads();
    for (int d = 1; d < 1024; d <<= 1) {
        int v = (t >= d) ? lds[t - d] : 0;
        __syncthreads();
        lds[t] += v;
        __syncthreads();
    }
    int run = (t == 0) ? 0 : lds[t - 1];
    for (int i = b; i < e; i++) {
        off[i] = run; cursor[i] = run; run += cnt[i];
    }
    if (t == 1023) off[n] = lds[1023];   // == total counted edges (<= E)
}

// ---------- kernel 3: scatter edge srcs into CSR order (guarded) ----------
__global__ void k_scatter(const int* __restrict__ ei, int* __restrict__ cursor,
                          int* __restrict__ srcs, int E) {
    int e = blockIdx.x * blockDim.x + threadIdx.x;
    if (e < E) {
        unsigned s = (unsigned)ei[2 * e];
        unsigned d = (unsigned)ei[2 * e + 1];
        if (d < (unsigned)N_NODES && s < (unsigned)N_NODES) {
            unsigned pos = (unsigned)atomicAdd(&cursor[d], 1);
            if (pos < (unsigned)E) srcs[pos] = (int)s;
        }
    }
}

// ---------- kernel 4: build bf16 B-fragment-swizzled weights (1D, one tensor) ----------
// Wb element index: frag*512 + lane*8 + j, frag = kb*16 + nt  (kb in [0,16), nt in [0,16))
// maps to B[k][n]: k = kb*32 + (lane>>4)*8 + j,  n = nt*16 + (lane&15)
// B[k][n] = k<256 ? Wl[n*256+k] : Wr[n*256+k-256]
__global__ void k_wt(const float* __restrict__ Wl, const float* __restrict__ Wr,
                     unsigned short* __restrict__ Wb) {
    int id = blockIdx.x * blockDim.x + threadIdx.x;   // [0, 131072)
    int j    = id & 7;
    int lane = (id >> 3) & 63;
    int frag = id >> 9;
    int nt   = frag & 15;
    int kb   = frag >> 4;
    int k = kb * 32 + (lane >> 4) * 8 + j;
    int n = nt * 16 + (lane & 15);
    float v = (k < 256) ? Wl[n * 256 + k] : Wr[n * 256 + (k - 256)];
    Wb[id] = f2bf(v);
}

// ---------- kernel 5: fused aggregation + MFMA GEMM ----------
__global__ __launch_bounds__(256, 4)
void k_fused(const float* __restrict__ x_obj, const float* __restrict__ x_rel,
             const unsigned short* __restrict__ Wb_obj, const unsigned short* __restrict__ Wb_rel,
             const float* __restrict__ b_obj, const float* __restrict__ b_rel,
             const int* __restrict__ off, const int* __restrict__ srcs,
             float* __restrict__ out, int n) {
    __shared__ unsigned short A[MT][AROW];     // 32 x 520 bf16 = 33,280 B

    const int tz = blockIdx.y;
    const float* __restrict__ x   = tz ? x_rel  : x_obj;
    const unsigned short* __restrict__ Wb = tz ? Wb_rel : Wb_obj;
    const float* __restrict__ bia = tz ? b_rel  : b_obj;
    float* __restrict__ outp = out + (size_t)tz * (size_t)N_NODES * DFEAT;

    const int t = threadIdx.x;
    const int wave = t >> 6, lane = t & 63;
    const int node0 = blockIdx.x * MT;

    // ---- phase 1: per-node mean aggregation + x staging into LDS (bf16) ----
    const float4* __restrict__ x4 = (const float4*)x;
    for (int il = wave; il < MT; il += 4) {
        int node = node0 + il;
        float4 accv = make_float4(0.f, 0.f, 0.f, 0.f);
        float4 xv   = make_float4(0.f, 0.f, 0.f, 0.f);
        if (node < n) {
            xv = x4[(size_t)node * 64 + lane];
            int eb = off[node], ee = off[node + 1];
            if (eb < 0) eb = 0;
            if (ee > N_EDGES) ee = N_EDGES;
            if (ee < eb) ee = eb;
            int e = eb;
            for (; e + 1 < ee; e += 2) {             // 2-edge unroll: 2 gathers in flight
                unsigned s0 = (unsigned)srcs[e], s1 = (unsigned)srcs[e + 1];
                if (s0 >= (unsigned)n) s0 = 0;
                if (s1 >= (unsigned)n) s1 = 0;
                float4 v0 = x4[(size_t)s0 * 64 + lane];
                float4 v1 = x4[(size_t)s1 * 64 + lane];
                accv.x += v0.x + v1.x; accv.y += v0.y + v1.y;
                accv.z += v0.z + v1.z; accv.w += v0.w + v1.w;
            }
            if (e < ee) {
                unsigned s0 = (unsigned)srcs[e];
                if (s0 >= (unsigned)n) s0 = 0;
                float4 v = x4[(size_t)s0 * 64 + lane];
                accv.x += v.x; accv.y += v.y; accv.z += v.z; accv.w += v.w;
            }
            float c = (float)(ee - eb);
            float inv = 1.0f / fmaxf(c, 1.0f);
            accv.x *= inv; accv.y *= inv; accv.z *= inv; accv.w *= inv;
        }
        ushort4 a16 = make_ushort4(f2bf(accv.x), f2bf(accv.y), f2bf(accv.z), f2bf(accv.w));
        ushort4 x16 = make_ushort4(f2bf(xv.x),  f2bf(xv.y),  f2bf(xv.z),  f2bf(xv.w));
        *(ushort4*)&A[il][4 * lane]       = a16;   // agg in k-cols [0,256)
        *(ushort4*)&A[il][256 + 4 * lane] = x16;   // x   in k-cols [256,512)
    }
    __syncthreads();

    // ---- phase 2: 32x256 MFMA GEMM ----
    // wave w: row tile r0=(w&1)*16 ; col tiles nt0..nt0+7, nt0=(w>>1)*8
    const int r0  = (wave & 1) * 16;
    const int nt0 = (wave >> 1) * 8;
    const int lq  = lane >> 4;      // quad
    const int lm  = lane & 15;

    f32x4 acc[8];
    #pragma unroll
    for (int ct = 0; ct < 8; ct++) {
        float b = bia[(nt0 + ct) * 16 + lm];
        acc[ct] = (f32x4){b, b, b, b};
    }

    const bf16x8* __restrict__ Wb8 = (const bf16x8*)Wb;
    #pragma unroll
    for (int kb = 0; kb < 16; kb++) {
        bf16x8 af = *(const bf16x8*)&A[r0 + lm][kb * 32 + lq * 8];
        #pragma unroll
        for (int ct = 0; ct < 8; ct++) {
            bf16x8 bf = Wb8[(size_t)(kb * 16 + nt0 + ct) * 64 + lane];
            acc[ct] = __builtin_amdgcn_mfma_f32_16x16x32_bf16(af, bf, acc[ct], 0, 0, 0);
        }
    }

    // ---- writeback: C/D layout col=lane&15, row=quad*4+reg ----
    #pragma unroll
    for (int ct = 0; ct < 8; ct++) {
        int col = (nt0 + ct) * 16 + lm;
        #pragma unroll
        for (int r = 0; r < 4; r++) {
            int node = node0 + r0 + lq * 4 + r;
            if (node < n) outp[((size_t)node << 8) + col] = acc[ct][r];
        }
    }
}

extern "C" void kernel_launch(void* const* d_in, const int* in_sizes, int n_in,
                              void* d_out, int out_size, void* d_ws, size_t ws_size,
                              hipStream_t stream) {
    const float* obj  = (const float*)d_in[0];
    const float* rel  = (const float*)d_in[1];
    const int*   ei   = (const int*)d_in[2];
    const float* Wl_o = (const float*)d_in[3];
    const float* bl_o = (const float*)d_in[4];
    const float* Wr_o = (const float*)d_in[5];
    const float* Wl_r = (const float*)d_in[6];
    const float* bl_r = (const float*)d_in[7];
    const float* Wr_r = (const float*)d_in[8];
    float* out = (float*)d_out;

    char* w = (char*)d_ws;
    size_t o = 0;
    auto alloc = [&](size_t b) { size_t r = o; o += (b + 255) & ~(size_t)255; return r; };
    // NOTE: cnt/off/cursor/srcs are allocated CONTIGUOUSLY and zeroed as one block.
    size_t csr_base = o;
    int*            cnt    = (int*)(w + alloc((size_t)N_NODES * 4));
    int*            off    = (int*)(w + alloc((size_t)(N_NODES + 1) * 4));
    int*            cursor = (int*)(w + alloc((size_t)N_NODES * 4));
    int*            srcs   = (int*)(w + alloc((size_t)N_EDGES * 4));
    size_t csr_bytes = o - csr_base;                       // multiple of 256
    unsigned short* Wb_o   = (unsigned short*)(w + alloc((size_t)KCAT * DFEAT * 2));
    unsigned short* Wb_r   = (unsigned short*)(w + alloc((size_t)KCAT * DFEAT * 2));

    int n4 = (int)(csr_bytes / 16);
    k_zero<<<512, 256, 0, stream>>>((int4*)(w + csr_base), n4);
    k_hist<<<(N_EDGES + 255) / 256, 256, 0, stream>>>(ei, cnt, N_EDGES);
    k_scan<<<1, 1024, 0, stream>>>(cnt, off, cursor, N_NODES, N_EDGES);
    k_scatter<<<(N_EDGES + 255) / 256, 256, 0, stream>>>(ei, cursor, srcs, N_EDGES);
    k_wt<<<(KCAT * DFEAT) / 256, 256, 0, stream>>>(Wl_o, Wr_o, Wb_o);
    k_wt<<<(KCAT * DFEAT) / 256, 256, 0, stream>>>(Wl_r, Wr_r, Wb_r);

    dim3 g((N_NODES + MT - 1) / MT, 2);
    k_fused<<<g, 256, 0, stream>>>(obj, rel, Wb_o, Wb_r, bl_o, bl_r, off, srcs, out, N_NODES);
}

// Round 4
// 349.473 us; speedup vs baseline: 2.6515x; 1.3205x over previous
//
#include <hip/hip_runtime.h>

#define N_NODES 50000
#define N_EDGES 300000
#define DFEAT 256
#define KCAT 512
#define MT 32          // nodes per block in fused kernel
#define APAD 8         // bf16 row padding: row stride 520*2=1040 B
#define AROW (KCAT + APAD)
#define SCAN_NBLK ((N_NODES + 255) / 256)   // 196

typedef __attribute__((ext_vector_type(8))) short bf16x8;
typedef __attribute__((ext_vector_type(4))) float f32x4;

__device__ __forceinline__ unsigned short f2bf(float f) {
    union { float f; unsigned int u; } c; c.f = f;
    unsigned int r = c.u + 0x7FFF + ((c.u >> 16) & 1);   // round-to-nearest-even
    return (unsigned short)(r >> 16);
}

// ---------- kernel 0: zero the CSR workspace region ----------
__global__ void k_zero(int4* __restrict__ p, int n4) {
    int i = blockIdx.x * blockDim.x + threadIdx.x;
    int stride = gridDim.x * blockDim.x;
    for (; i < n4; i += stride) p[i] = make_int4(0, 0, 0, 0);
}

// ---------- kernel 1: histogram of dst (guarded) ----------
__global__ void k_hist(const int* __restrict__ ei, int* __restrict__ cnt, int E) {
    int e = blockIdx.x * blockDim.x + threadIdx.x;
    if (e < E) {
        unsigned d = (unsigned)ei[2 * e + 1];
        if (d < (unsigned)N_NODES) atomicAdd(&cnt[d], 1);
    }
}

// ---------- kernel 2a: per-block sums of cnt (coalesced) ----------
__global__ void k_scan_a(const int* __restrict__ cnt, int* __restrict__ bsum, int n) {
    int b = blockIdx.x, t = threadIdx.x;
    int i = b * 256 + t;
    int v = (i < n) ? cnt[i] : 0;
    #pragma unroll
    for (int d = 32; d; d >>= 1) v += __shfl_down(v, d, 64);
    __shared__ int ws[4];
    if ((t & 63) == 0) ws[t >> 6] = v;
    __syncthreads();
    if (t == 0) bsum[b] = ws[0] + ws[1] + ws[2] + ws[3];
}

// ---------- kernel 2b: scan the block sums (1 block), also writes off[n] ----------
__global__ void k_scan_b(const int* __restrict__ bsum, int* __restrict__ bpre,
                         int* __restrict__ off, int nblk, int n) {
    __shared__ int lds[256];
    int t = threadIdx.x;
    int v = (t < nblk) ? bsum[t] : 0;
    lds[t] = v;
    __syncthreads();
    for (int d = 1; d < 256; d <<= 1) {
        int u = (t >= d) ? lds[t - d] : 0;
        __syncthreads();
        lds[t] += u;
        __syncthreads();
    }
    if (t < nblk) bpre[t] = lds[t] - v;      // exclusive prefix of block sums
    if (t == 255) off[n] = lds[255];         // total counted edges
}

// ---------- kernel 2c: per-block exclusive scan + offset, write off/cursor ----------
__global__ void k_scan_c(const int* __restrict__ cnt, const int* __restrict__ bpre,
                         int* __restrict__ off, int* __restrict__ cursor, int n) {
    __shared__ int lds[256];
    int b = blockIdx.x, t = threadIdx.x;
    int i = b * 256 + t;
    int v = (i < n) ? cnt[i] : 0;
    lds[t] = v;
    __syncthreads();
    for (int d = 1; d < 256; d <<= 1) {
        int u = (t >= d) ? lds[t - d] : 0;
        __syncthreads();
        lds[t] += u;
        __syncthreads();
    }
    if (i < n) {
        int ex = bpre[b] + lds[t] - v;
        off[i] = ex;
        cursor[i] = ex;
    }
}

// ---------- kernel 3: scatter edge srcs into CSR order (guarded) ----------
__global__ void k_scatter(const int* __restrict__ ei, int* __restrict__ cursor,
                          int* __restrict__ srcs, int E) {
    int e = blockIdx.x * blockDim.x + threadIdx.x;
    if (e < E) {
        unsigned s = (unsigned)ei[2 * e];
        unsigned d = (unsigned)ei[2 * e + 1];
        if (d < (unsigned)N_NODES && s < (unsigned)N_NODES) {
            unsigned pos = (unsigned)atomicAdd(&cursor[d], 1);
            if (pos < (unsigned)E) srcs[pos] = (int)s;
        }
    }
}

// ---------- kernel 4: build bf16 B-fragment-swizzled weights ----------
// Wb element index: frag*512 + lane*8 + j, frag = kb*16 + nt
// maps to B[k][n]: k = kb*32 + (lane>>4)*8 + j,  n = nt*16 + (lane&15)
__global__ void k_wt(const float* __restrict__ Wl, const float* __restrict__ Wr,
                     unsigned short* __restrict__ Wb) {
    int id = blockIdx.x * blockDim.x + threadIdx.x;   // [0, 131072)
    int j    = id & 7;
    int lane = (id >> 3) & 63;
    int frag = id >> 9;
    int nt   = frag & 15;
    int kb   = frag >> 4;
    int k = kb * 32 + (lane >> 4) * 8 + j;
    int n = nt * 16 + (lane & 15);
    float v = (k < 256) ? Wl[n * 256 + k] : Wr[n * 256 + (k - 256)];
    Wb[id] = f2bf(v);
}

// ---------- kernel 5: fused aggregation + MFMA GEMM ----------
__global__ __launch_bounds__(256, 4)
void k_fused(const float* __restrict__ x_obj, const float* __restrict__ x_rel,
             const unsigned short* __restrict__ Wb_obj, const unsigned short* __restrict__ Wb_rel,
             const float* __restrict__ b_obj, const float* __restrict__ b_rel,
             const int* __restrict__ off, const int* __restrict__ srcs,
             float* __restrict__ out, int n) {
    __shared__ unsigned short A[MT][AROW];     // 32 x 520 bf16 = 33,280 B

    const int tz = blockIdx.y;
    const float* __restrict__ x   = tz ? x_rel  : x_obj;
    const unsigned short* __restrict__ Wb = tz ? Wb_rel : Wb_obj;
    const float* __restrict__ bia = tz ? b_rel  : b_obj;
    float* __restrict__ outp = out + (size_t)tz * (size_t)N_NODES * DFEAT;

    const int t = threadIdx.x;
    const int wave = t >> 6, lane = t & 63;
    const int node0 = blockIdx.x * MT;

    // ---- phase 1: per-node mean aggregation + x staging into LDS (bf16) ----
    const float4* __restrict__ x4 = (const float4*)x;
    for (int il = wave; il < MT; il += 4) {
        int node = node0 + il;
        float4 accv = make_float4(0.f, 0.f, 0.f, 0.f);
        float4 xv   = make_float4(0.f, 0.f, 0.f, 0.f);
        if (node < n) {
            xv = x4[(size_t)node * 64 + lane];
            int eb = off[node], ee = off[node + 1];
            if (eb < 0) eb = 0;
            if (ee > N_EDGES) ee = N_EDGES;
            if (ee < eb) ee = eb;
            int e = eb;
            for (; e + 3 < ee; e += 4) {             // 4 gathers in flight
                unsigned s0 = (unsigned)srcs[e],     s1 = (unsigned)srcs[e + 1];
                unsigned s2 = (unsigned)srcs[e + 2], s3 = (unsigned)srcs[e + 3];
                if (s0 >= (unsigned)n) s0 = 0;
                if (s1 >= (unsigned)n) s1 = 0;
                if (s2 >= (unsigned)n) s2 = 0;
                if (s3 >= (unsigned)n) s3 = 0;
                float4 v0 = x4[(size_t)s0 * 64 + lane];
                float4 v1 = x4[(size_t)s1 * 64 + lane];
                float4 v2 = x4[(size_t)s2 * 64 + lane];
                float4 v3 = x4[(size_t)s3 * 64 + lane];
                accv.x += (v0.x + v1.x) + (v2.x + v3.x);
                accv.y += (v0.y + v1.y) + (v2.y + v3.y);
                accv.z += (v0.z + v1.z) + (v2.z + v3.z);
                accv.w += (v0.w + v1.w) + (v2.w + v3.w);
            }
            if (e + 1 < ee) {                        // 2-edge remainder
                unsigned s0 = (unsigned)srcs[e], s1 = (unsigned)srcs[e + 1];
                if (s0 >= (unsigned)n) s0 = 0;
                if (s1 >= (unsigned)n) s1 = 0;
                float4 v0 = x4[(size_t)s0 * 64 + lane];
                float4 v1 = x4[(size_t)s1 * 64 + lane];
                accv.x += v0.x + v1.x; accv.y += v0.y + v1.y;
                accv.z += v0.z + v1.z; accv.w += v0.w + v1.w;
                e += 2;
            }
            if (e < ee) {                            // 1-edge remainder
                unsigned s0 = (unsigned)srcs[e];
                if (s0 >= (unsigned)n) s0 = 0;
                float4 v = x4[(size_t)s0 * 64 + lane];
                accv.x += v.x; accv.y += v.y; accv.z += v.z; accv.w += v.w;
            }
            float c = (float)(ee - eb);
            float inv = 1.0f / fmaxf(c, 1.0f);
            accv.x *= inv; accv.y *= inv; accv.z *= inv; accv.w *= inv;
        }
        ushort4 a16 = make_ushort4(f2bf(accv.x), f2bf(accv.y), f2bf(accv.z), f2bf(accv.w));
        ushort4 x16 = make_ushort4(f2bf(xv.x),  f2bf(xv.y),  f2bf(xv.z),  f2bf(xv.w));
        *(ushort4*)&A[il][4 * lane]       = a16;   // agg in k-cols [0,256)
        *(ushort4*)&A[il][256 + 4 * lane] = x16;   // x   in k-cols [256,512)
    }
    __syncthreads();

    // ---- phase 2: 32x256 MFMA GEMM ----
    const int r0  = (wave & 1) * 16;
    const int nt0 = (wave >> 1) * 8;
    const int lq  = lane >> 4;
    const int lm  = lane & 15;

    f32x4 acc[8];
    #pragma unroll
    for (int ct = 0; ct < 8; ct++) {
        float b = bia[(nt0 + ct) * 16 + lm];
        acc[ct] = (f32x4){b, b, b, b};
    }

    const bf16x8* __restrict__ Wb8 = (const bf16x8*)Wb;
    #pragma unroll
    for (int kb = 0; kb < 16; kb++) {
        bf16x8 af = *(const bf16x8*)&A[r0 + lm][kb * 32 + lq * 8];
        #pragma unroll
        for (int ct = 0; ct < 8; ct++) {
            bf16x8 bf = Wb8[(size_t)(kb * 16 + nt0 + ct) * 64 + lane];
            acc[ct] = __builtin_amdgcn_mfma_f32_16x16x32_bf16(af, bf, acc[ct], 0, 0, 0);
        }
    }

    // ---- writeback: C/D layout col=lane&15, row=quad*4+reg ----
    #pragma unroll
    for (int ct = 0; ct < 8; ct++) {
        int col = (nt0 + ct) * 16 + lm;
        #pragma unroll
        for (int r = 0; r < 4; r++) {
            int node = node0 + r0 + lq * 4 + r;
            if (node < n) outp[((size_t)node << 8) + col] = acc[ct][r];
        }
    }
}

extern "C" void kernel_launch(void* const* d_in, const int* in_sizes, int n_in,
                              void* d_out, int out_size, void* d_ws, size_t ws_size,
                              hipStream_t stream) {
    const float* obj  = (const float*)d_in[0];
    const float* rel  = (const float*)d_in[1];
    const int*   ei   = (const int*)d_in[2];
    const float* Wl_o = (const float*)d_in[3];
    const float* bl_o = (const float*)d_in[4];
    const float* Wr_o = (const float*)d_in[5];
    const float* Wl_r = (const float*)d_in[6];
    const float* bl_r = (const float*)d_in[7];
    const float* Wr_r = (const float*)d_in[8];
    float* out = (float*)d_out;

    char* w = (char*)d_ws;
    size_t o = 0;
    auto alloc = [&](size_t b) { size_t r = o; o += (b + 255) & ~(size_t)255; return r; };
    size_t csr_base = o;
    int*            cnt    = (int*)(w + alloc((size_t)N_NODES * 4));
    int*            off    = (int*)(w + alloc((size_t)(N_NODES + 1) * 4));
    int*            cursor = (int*)(w + alloc((size_t)N_NODES * 4));
    int*            srcs   = (int*)(w + alloc((size_t)N_EDGES * 4));
    size_t csr_bytes = o - csr_base;                       // multiple of 256
    int*            bsum   = (int*)(w + alloc(256 * 4));
    int*            bpre   = (int*)(w + alloc(256 * 4));
    unsigned short* Wb_o   = (unsigned short*)(w + alloc((size_t)KCAT * DFEAT * 2));
    unsigned short* Wb_r   = (unsigned short*)(w + alloc((size_t)KCAT * DFEAT * 2));

    int n4 = (int)(csr_bytes / 16);
    k_zero<<<512, 256, 0, stream>>>((int4*)(w + csr_base), n4);
    k_hist<<<(N_EDGES + 255) / 256, 256, 0, stream>>>(ei, cnt, N_EDGES);
    k_scan_a<<<SCAN_NBLK, 256, 0, stream>>>(cnt, bsum, N_NODES);
    k_scan_b<<<1, 256, 0, stream>>>(bsum, bpre, off, SCAN_NBLK, N_NODES);
    k_scan_c<<<SCAN_NBLK, 256, 0, stream>>>(cnt, bpre, off, cursor, N_NODES);
    k_scatter<<<(N_EDGES + 255) / 256, 256, 0, stream>>>(ei, cursor, srcs, N_EDGES);
    k_wt<<<(KCAT * DFEAT) / 256, 256, 0, stream>>>(Wl_o, Wr_o, Wb_o);
    k_wt<<<(KCAT * DFEAT) / 256, 256, 0, stream>>>(Wl_r, Wr_r, Wb_r);

    dim3 g((N_NODES + MT - 1) / MT, 2);
    k_fused<<<g, 256, 0, stream>>>(obj, rel, Wb_o, Wb_r, bl_o, bl_r, off, srcs, out, N_NODES);
}